// Round 10
// baseline (198.216 us; speedup 1.0000x reference)
//
#include <hip/hip_runtime.h>

// UniformKernel: per-column (dim) moving average (K=10, replicate pad) over
// bins axis (n_bins=2048) + per-column normalization. x: (NB, DIM) f32.
//
// out(b,d) = window_sum(b,d) / (width * sum_i w[i]*x[i,d]),
// w[i] = # windows covering row i under edge clamping (K cancels).
//
// R10: R9 (124us) sits exactly at the SERIALIZED-phase bound (~43us read +
// ~42us write + L3 reread, no read/write overlap: all blocks read-phase,
// then all write-phase). This version software-pipelines two column-halves
// per block:  S1: colsum(H0) -> sc0;  S3: ring+store(H0) INTERLEAVED with
// colsum-loads(H1) -> chip-wide read/write mixing;  S4: reduce -> sc1;
// S5: ring+store(H1). Trades 512B->256B wave segments (~-5%, R6 vs R9)
// for phase overlap (~+25% if fabric mixes reads+writes well).

constexpr int NB    = 2048;
constexpr int DIM   = 32768;
constexpr int DIM4  = DIM / 4;

constexpr int W4    = 32;            // stripe width per block (float4)
constexpr int H4    = 16;            // half-stripe width
constexpr int NBLK  = DIM4 / W4;     // 256 blocks = 1 per CU
constexpr int NTHR  = 1024;
constexpr int RGH   = NTHR / H4;     // 64 row-groups per half
constexpr int ROWSH = NB / RGH;      // 32 rows per thread per half

typedef float v4f __attribute__((ext_vector_type(4)));

__device__ __forceinline__ int clampb(int j) { return min(max(j, 0), NB - 1); }

// # windows covering row i (interior=10; head 15,6,7,8,9; tail 9,8,7,21).
__device__ __forceinline__ float wrow(int i) {
    int a = min(i + 4, NB - 1) - max(i - 5, 0) + 1;
    if (i == 0)      a += 10;
    if (i == NB - 1) a += 15;
    return (float)a;
}

__global__ __launch_bounds__(NTHR, 4) void k_pipe(const float* __restrict__ x,
                                                  const float* __restrict__ bins,
                                                  float* __restrict__ out) {
    const int t   = threadIdx.x;
    const int ch  = t & (H4 - 1);         // column within half (0..15)
    const int rgh = t >> 4;               // row group (0..63)
    const int b0  = rgh * ROWSH;          // first row of this thread's strip
    const size_t col0 = (size_t)blockIdx.x * W4 + ch;
    const v4f* __restrict__ px0 = reinterpret_cast<const v4f*>(x) + col0;
    const v4f* __restrict__ px1 = px0 + H4;
    v4f* __restrict__ po0 = reinterpret_cast<v4f*>(out) + col0;
    v4f* __restrict__ po1 = po0 + H4;

    __shared__ v4f sums[RGH][H4];         // 16 KB
    const bool edge = (rgh == 0) || (rgh == RGH - 1);
    constexpr int MAINH = ROWSH - (ROWSH % 10);  // 30
    constexpr int TAILH = ROWSH % 10;            // 2

    // ---- S1: column sums over H0 (pure read phase, short: 1/4 of x) ----
    {
        v4f acc = {0.f, 0.f, 0.f, 0.f};
        if (edge) {
            #pragma unroll 8
            for (int i = b0; i < b0 + ROWSH; ++i)
                acc += wrow(i) * px0[(size_t)i * DIM4];
        } else {
            #pragma unroll 8
            for (int i = b0; i < b0 + ROWSH; ++i)
                acc += px0[(size_t)i * DIM4];
            acc *= 10.f;
        }
        sums[rgh][ch] = acc;
    }
    __syncthreads();
    #pragma unroll
    for (int s = RGH / 2; s > 0; s >>= 1) {
        if (rgh < s) sums[rgh][ch] += sums[rgh + s][ch];
        __syncthreads();
    }
    const float width = bins[1] - bins[0];
    v4f sc0;
    {
        const v4f ws = sums[0][ch];
        sc0.x = 1.f / (width * ws.x);
        sc0.y = 1.f / (width * ws.y);
        sc0.z = 1.f / (width * ws.z);
        sc0.w = 1.f / (width * ws.w);
    }

    // ---- S3: ring-window + stores on H0, interleaved with colsum loads of
    // H1 (reads and writes mix on the fabric) ----
    v4f acc1 = {0.f, 0.f, 0.f, 0.f};
    v4f prev[10], cur[10], a1[10];
    #pragma unroll
    for (int m = 0; m < 10; ++m)
        prev[m] = px0[(size_t)clampb(b0 - 4 + m) * DIM4];
    v4f S = prev[0];
    #pragma unroll
    for (int m = 1; m < 10; ++m) S += prev[m];

    for (int t0 = 0; t0 < MAINH; t0 += 10) {
        #pragma unroll
        for (int m = 0; m < 10; ++m)
            cur[m] = px0[(size_t)min(b0 + t0 + m + 6, NB - 1) * DIM4];
        #pragma unroll
        for (int m = 0; m < 10; ++m)
            a1[m] = px1[(size_t)(b0 + t0 + m) * DIM4];
        #pragma unroll
        for (int m = 0; m < 10; ++m) {
            v4f o = S * sc0;
            __builtin_nontemporal_store(o, po0 + (size_t)(b0 + t0 + m) * DIM4);
            S += cur[m] - prev[m];
            prev[m] = cur[m];
            if (edge) acc1 += wrow(b0 + t0 + m) * a1[m];
            else      acc1 += a1[m];
        }
    }
    #pragma unroll
    for (int m = 0; m < TAILH; ++m) {
        cur[m] = px0[(size_t)min(b0 + MAINH + m + 6, NB - 1) * DIM4];
        a1[m]  = px1[(size_t)(b0 + MAINH + m) * DIM4];
    }
    #pragma unroll
    for (int m = 0; m < TAILH; ++m) {
        v4f o = S * sc0;
        __builtin_nontemporal_store(o, po0 + (size_t)(b0 + MAINH + m) * DIM4);
        S += cur[m] - prev[m];
        if (edge) acc1 += wrow(b0 + MAINH + m) * a1[m];
        else      acc1 += a1[m];
    }
    if (!edge) acc1 *= 10.f;

    // ---- S4: reduce H1 sums -> sc1 ----
    __syncthreads();              // all reads of sums[0] (sc0) long done
    sums[rgh][ch] = acc1;
    __syncthreads();
    #pragma unroll
    for (int s = RGH / 2; s > 0; s >>= 1) {
        if (rgh < s) sums[rgh][ch] += sums[rgh + s][ch];
        __syncthreads();
    }
    v4f sc1;
    {
        const v4f ws = sums[0][ch];
        sc1.x = 1.f / (width * ws.x);
        sc1.y = 1.f / (width * ws.y);
        sc1.z = 1.f / (width * ws.z);
        sc1.w = 1.f / (width * ws.w);
    }

    // ---- S5: ring-window + stores on H1 (reads are L3-warm from S3) ----
    #pragma unroll
    for (int m = 0; m < 10; ++m)
        prev[m] = px1[(size_t)clampb(b0 - 4 + m) * DIM4];
    S = prev[0];
    #pragma unroll
    for (int m = 1; m < 10; ++m) S += prev[m];

    for (int t0 = 0; t0 < MAINH; t0 += 10) {
        #pragma unroll
        for (int m = 0; m < 10; ++m)
            cur[m] = px1[(size_t)min(b0 + t0 + m + 6, NB - 1) * DIM4];
        #pragma unroll
        for (int m = 0; m < 10; ++m) {
            v4f o = S * sc1;
            __builtin_nontemporal_store(o, po1 + (size_t)(b0 + t0 + m) * DIM4);
            S += cur[m] - prev[m];
            prev[m] = cur[m];
        }
    }
    #pragma unroll
    for (int m = 0; m < TAILH; ++m)
        cur[m] = px1[(size_t)min(b0 + MAINH + m + 6, NB - 1) * DIM4];
    #pragma unroll
    for (int m = 0; m < TAILH; ++m) {
        v4f o = S * sc1;
        __builtin_nontemporal_store(o, po1 + (size_t)(b0 + MAINH + m) * DIM4);
        S += cur[m] - prev[m];
    }
}

extern "C" void kernel_launch(void* const* d_in, const int* in_sizes, int n_in,
                              void* d_out, int out_size, void* d_ws, size_t ws_size,
                              hipStream_t stream) {
    const float* x    = (const float*)d_in[0];   // densities (NB, DIM)
    const float* bins = (const float*)d_in[1];   // (NB,)
    float* out = (float*)d_out;
    k_pipe<<<dim3(NBLK), dim3(NTHR), 0, stream>>>(x, bins, out);
}

// Round 11
// 158.914 us; speedup vs baseline: 1.2473x; 1.2473x over previous
//
#include <hip/hip_runtime.h>

// UniformKernel: per-column (dim) moving average (K=10, replicate pad) over
// bins axis (n_bins=2048) + per-column normalization. x: (NB, DIM) f32.
//
// out(b,d) = window_sum(b,d) / (width * sum_i w[i]*x[i,d]),
// w[i] = # windows covering row i under edge clamping (K cancels).
//
// R11: phase-overlap pipeline (R10 idea) rebuilt register-lean. R10 spilled
// (needed ~120 live VGPRs vs 128 cap for 1024-thr blocks; FETCH/WRITE
// +90/+132 MB of scratch traffic). Changes: (a) no register ring -- the
// x[b-4] subtrahend is reloaded from cache (L1/L2-warm: loaded as cur 10
// rows earlier; stripe L3-resident), freeing ~80 regs; (b) interleave depth
// 4: 12 loads in flight = 48 regs. Stages: S1 colsum(H0)->sc0; S3 window+
// store(H0) interleaved with colsum loads(H1) -> chip-wide read/write mix;
// S4 reduce->sc1; S5 window+store(H1) (all reads warm).

constexpr int NB    = 2048;
constexpr int DIM   = 32768;
constexpr int DIM4  = DIM / 4;

constexpr int W4    = 32;            // stripe width per block (float4)
constexpr int H4    = 16;            // half-stripe width
constexpr int NBLK  = DIM4 / W4;     // 256 blocks
constexpr int NTHR  = 1024;
constexpr int RGH   = NTHR / H4;     // 64 row-groups per half
constexpr int ROWSH = NB / RGH;      // 32 rows per thread per half
constexpr int G     = 4;             // interleave depth (12 loads in flight)

typedef float v4f __attribute__((ext_vector_type(4)));

__device__ __forceinline__ int clampb(int j) { return min(max(j, 0), NB - 1); }

// # windows covering row i (interior=10; head 15,6,7,8,9; tail 9,8,7,21).
__device__ __forceinline__ float wrow(int i) {
    int a = min(i + 4, NB - 1) - max(i - 5, 0) + 1;
    if (i == 0)      a += 10;
    if (i == NB - 1) a += 15;
    return (float)a;
}

__global__ __launch_bounds__(NTHR, 4) void k_pipe(const float* __restrict__ x,
                                                  const float* __restrict__ bins,
                                                  float* __restrict__ out) {
    const int t   = threadIdx.x;
    const int ch  = t & (H4 - 1);         // column within half (0..15)
    const int rgh = t >> 4;               // row group (0..63)
    const int b0  = rgh * ROWSH;          // first row of this thread's strip
    const size_t col0 = (size_t)blockIdx.x * W4 + ch;
    const v4f* __restrict__ px0 = reinterpret_cast<const v4f*>(x) + col0;
    const v4f* __restrict__ px1 = px0 + H4;
    v4f* __restrict__ po0 = reinterpret_cast<v4f*>(out) + col0;
    v4f* __restrict__ po1 = po0 + H4;

    __shared__ v4f sums[RGH][H4];         // 16 KB
    const bool edge = (rgh == 0) || (rgh == RGH - 1);
    const float width = bins[1] - bins[0];

    // ---- S1: column sums over H0 (short pure-read phase: 1/4 of x) ----
    {
        v4f acc = {0.f, 0.f, 0.f, 0.f};
        if (edge) {
            #pragma unroll 8
            for (int i = b0; i < b0 + ROWSH; ++i)
                acc += wrow(i) * px0[(size_t)i * DIM4];
        } else {
            #pragma unroll 8
            for (int i = b0; i < b0 + ROWSH; ++i)
                acc += px0[(size_t)i * DIM4];
            acc *= 10.f;
        }
        sums[rgh][ch] = acc;
    }
    __syncthreads();
    #pragma unroll
    for (int s = RGH / 2; s > 0; s >>= 1) {
        if (rgh < s) sums[rgh][ch] += sums[rgh + s][ch];
        __syncthreads();
    }
    v4f sc0;
    {
        const v4f ws = sums[0][ch];
        sc0.x = 1.f / (width * ws.x);
        sc0.y = 1.f / (width * ws.y);
        sc0.z = 1.f / (width * ws.z);
        sc0.w = 1.f / (width * ws.w);
    }

    // ---- S3: window+store H0 interleaved with colsum loads of H1 ----
    v4f acc1 = {0.f, 0.f, 0.f, 0.f};
    v4f S;
    {
        S = px0[(size_t)clampb(b0 - 4) * DIM4];
        #pragma unroll
        for (int j = 1; j < 10; ++j)
            S += px0[(size_t)clampb(b0 - 4 + j) * DIM4];
    }
    for (int t0 = 0; t0 < ROWSH; t0 += G) {
        v4f pv[G], cu[G], av[G];
        #pragma unroll
        for (int m = 0; m < G; ++m) {
            const int b = b0 + t0 + m;
            pv[m] = px0[(size_t)clampb(b - 4) * DIM4];        // L1/L2 hit
            cu[m] = px0[(size_t)min(b + 6, NB - 1) * DIM4];   // L2/L3 hit
            av[m] = px1[(size_t)b * DIM4];                    // cold HBM
        }
        #pragma unroll
        for (int m = 0; m < G; ++m) {
            const int b = b0 + t0 + m;
            v4f o = S * sc0;
            __builtin_nontemporal_store(o, po0 + (size_t)b * DIM4);
            S += cu[m] - pv[m];
            if (edge) acc1 += wrow(b) * av[m];
            else      acc1 += av[m];
        }
    }
    if (!edge) acc1 *= 10.f;

    // ---- S4: reduce H1 sums -> sc1 ----
    __syncthreads();              // everyone done with sums[0] and S3
    sums[rgh][ch] = acc1;
    __syncthreads();
    #pragma unroll
    for (int s = RGH / 2; s > 0; s >>= 1) {
        if (rgh < s) sums[rgh][ch] += sums[rgh + s][ch];
        __syncthreads();
    }
    v4f sc1;
    {
        const v4f ws = sums[0][ch];
        sc1.x = 1.f / (width * ws.x);
        sc1.y = 1.f / (width * ws.y);
        sc1.z = 1.f / (width * ws.z);
        sc1.w = 1.f / (width * ws.w);
    }

    // ---- S5: window+store H1 (reads L2/L3-warm from S3) ----
    {
        S = px1[(size_t)clampb(b0 - 4) * DIM4];
        #pragma unroll
        for (int j = 1; j < 10; ++j)
            S += px1[(size_t)clampb(b0 - 4 + j) * DIM4];
    }
    for (int t0 = 0; t0 < ROWSH; t0 += G) {
        v4f pv[G], cu[G];
        #pragma unroll
        for (int m = 0; m < G; ++m) {
            const int b = b0 + t0 + m;
            pv[m] = px1[(size_t)clampb(b - 4) * DIM4];
            cu[m] = px1[(size_t)min(b + 6, NB - 1) * DIM4];
        }
        #pragma unroll
        for (int m = 0; m < G; ++m) {
            const int b = b0 + t0 + m;
            v4f o = S * sc1;
            __builtin_nontemporal_store(o, po1 + (size_t)b * DIM4);
            S += cu[m] - pv[m];
        }
    }
}

extern "C" void kernel_launch(void* const* d_in, const int* in_sizes, int n_in,
                              void* d_out, int out_size, void* d_ws, size_t ws_size,
                              hipStream_t stream) {
    const float* x    = (const float*)d_in[0];   // densities (NB, DIM)
    const float* bins = (const float*)d_in[1];   // (NB,)
    float* out = (float*)d_out;
    k_pipe<<<dim3(NBLK), dim3(NTHR), 0, stream>>>(x, bins, out);
}

// Round 12
// 105.294 us; speedup vs baseline: 1.8825x; 1.5092x over previous
//
#include <hip/hip_runtime.h>

// UniformKernel: per-column (dim) moving average (K=10, replicate pad) over
// bins axis (n_bins=2048) + per-column normalization. x: (NB, DIM) f32.
//
// out(b,d) = window_sum(b,d) / (width * sum_i w[i]*x[i,d]),
// w[i] = # windows covering row i under edge clamping (K cancels).
//
// R12: SINGLE-GLOBAL-READ design. Fabric model from R9/R11: time =
// total fabric bytes / ~6.4 TB/s; R9 moved 798 MB (x cold + x L3-reread +
// out) = 124us. This kernel holds each thread's 16 rows in REGISTERS
// (64 VGPR) across the colsum -> scale -> window phases: x is read from
// global exactly once (268 MB) and out written once (262 MB) = 530 MB
// => ~85us target. Window halos (rows +-4/+5) come from neighbor threads:
// same-wave via __shfl (lane+-8), wave-boundary via 18 KB LDS publish.
// All xv[] indexing is compile-time (full unroll) to stay in registers.

constexpr int NB   = 2048;
constexpr int DIM  = 32768;
constexpr int DIM4 = DIM / 4;

constexpr int W4   = 8;              // float4 columns per block stripe
constexpr int NBLK = DIM4 / W4;      // 1024 blocks
constexpr int NTHR = 1024;
constexpr int RG   = NTHR / W4;      // 128 row-groups
constexpr int RT   = NB / RG;        // 16 rows per thread (in registers)
constexpr int NW   = NTHR / 64;      // 16 waves

typedef float v4f __attribute__((ext_vector_type(4)));

// # windows covering row i (interior=10; head 15,6,7,8,9; tail 9,8,7,21).
__device__ __forceinline__ float wrow(int i) {
    int a = min(i + 4, NB - 1) - max(i - 5, 0) + 1;
    if (i == 0)      a += 10;
    if (i == NB - 1) a += 15;
    return (float)a;
}

__device__ __forceinline__ v4f shfl4(v4f v, int srcLane) {
    v4f r;
    r.x = __shfl(v.x, srcLane, 64);
    r.y = __shfl(v.y, srcLane, 64);
    r.z = __shfl(v.z, srcLane, 64);
    r.w = __shfl(v.w, srcLane, 64);
    return r;
}

__global__ __launch_bounds__(NTHR, 4) void k_regpass(const float* __restrict__ x,
                                                     const float* __restrict__ bins,
                                                     float* __restrict__ out) {
    const int t    = threadIdx.x;
    const int c    = t & (W4 - 1);        // column lane (0..7)
    const int rg   = t >> 3;              // row group (0..127)
    const int lane = t & 63;
    const int wave = t >> 6;              // 0..15
    const int rgw  = (lane >> 3);         // row group within wave (0..7)
    const int r0   = rg * RT;             // first row of this thread
    const v4f* __restrict__ px = reinterpret_cast<const v4f*>(x)
                                 + ((size_t)blockIdx.x * W4 + c);
    v4f* __restrict__ po = reinterpret_cast<v4f*>(out)
                           + ((size_t)blockIdx.x * W4 + c);

    __shared__ v4f sums[RG][W4];          // 16 KB
    __shared__ v4f pub_hi[NW][W4][4];     // wave-edge rgw==7: rows 12..15 (8 KB)
    __shared__ v4f pub_lo[NW][W4][5];     // wave-edge rgw==0: rows 0..4  (10 KB)

    // ---- single global read: rows -> registers, colsum on the fly ----
    v4f xv[RT];
    #pragma unroll
    for (int i = 0; i < RT; ++i)
        xv[i] = px[(size_t)(r0 + i) * DIM4];

    {
        v4f acc = {0.f, 0.f, 0.f, 0.f};
        if (rg == 0 || rg == RG - 1) {
            #pragma unroll
            for (int i = 0; i < RT; ++i) acc += wrow(r0 + i) * xv[i];
        } else {
            #pragma unroll
            for (int i = 0; i < RT; ++i) acc += xv[i];
            acc *= 10.f;
        }
        sums[rg][c] = acc;
    }
    // wave-boundary halo publish (only 2 threads per wave per column)
    if (rgw == 7) {
        #pragma unroll
        for (int j = 0; j < 4; ++j) pub_hi[wave][c][j] = xv[12 + j];
    }
    if (rgw == 0) {
        #pragma unroll
        for (int j = 0; j < 5; ++j) pub_lo[wave][c][j] = xv[j];
    }
    __syncthreads();

    // ---- block-local tree reduce -> per-column scale ----
    #pragma unroll
    for (int s = RG / 2; s > 0; s >>= 1) {
        if (rg < s) sums[rg][c] += sums[rg + s][c];
        __syncthreads();
    }
    const float width = bins[1] - bins[0];
    v4f sc;
    {
        const v4f ws = sums[0][c];
        sc.x = 1.f / (width * ws.x);
        sc.y = 1.f / (width * ws.y);
        sc.z = 1.f / (width * ws.z);
        sc.w = 1.f / (width * ws.w);
    }

    // ---- halo gather: rows r0-4..r0-1 (below) ----
    // below j: neighbor rg-1's xv[12+j]; wave-edge via LDS; rg==0 replicates row 0.
    v4f b[4];
    {
        const int wlo = (wave > 0) ? wave - 1 : 0;
        #pragma unroll
        for (int j = 0; j < 4; ++j) {
            v4f s = shfl4(xv[12 + j], (lane - 8) & 63);
            v4f l = pub_hi[wlo][c][j];
            b[j] = (rgw == 0) ? ((rg == 0) ? xv[0] : l) : s;
        }
    }

    // ---- window pass: S = sum x[r-4..r+5], all from registers/halo ----
    v4f S = b[0] + b[1] + b[2] + b[3]
          + xv[0] + xv[1] + xv[2] + xv[3] + xv[4] + xv[5];

    const int whi = (wave < NW - 1) ? wave + 1 : NW - 1;
    #pragma unroll
    for (int r = 0; r < RT; ++r) {
        v4f o = S * sc;
        __builtin_nontemporal_store(o, po + (size_t)(r0 + r) * DIM4);
        if (r < RT - 1) {
            v4f nx;
            if (r < 10) {
                nx = xv[r + 6];
            } else {
                // row r0+16+(r-10): neighbor rg+1's xv[r-10]
                v4f s = shfl4(xv[r - 10], (lane + 8) & 63);
                v4f l = pub_lo[whi][c][r - 10];
                nx = (rgw == 7) ? ((rg == RG - 1) ? xv[15] : l) : s;
            }
            v4f dp = (r >= 4) ? xv[r - 4] : b[r];
            S += nx - dp;
        }
    }
}

extern "C" void kernel_launch(void* const* d_in, const int* in_sizes, int n_in,
                              void* d_out, int out_size, void* d_ws, size_t ws_size,
                              hipStream_t stream) {
    const float* x    = (const float*)d_in[0];   // densities (NB, DIM)
    const float* bins = (const float*)d_in[1];   // (NB,)
    float* out = (float*)d_out;
    k_regpass<<<dim3(NBLK), dim3(NTHR), 0, stream>>>(x, bins, out);
}